// Round 14
// baseline (58.577 us; speedup 1.0000x reference)
//
#include <hip/hip_runtime.h>
#include <cstdint>
#include <math.h>

namespace {

constexpr int QBLOCK = 64;
// jax: q = 0.95f * 63.0f -> f32 59.849998474121094
// high_weight = q - 59 = 0.84999847412109375 (exact), low_weight = 60 - q (exact)
constexpr float W59 = 0.15000152587890625f;  // weight for sorted[59] (5th largest)
constexpr float W60 = 0.84999847412109375f;  // weight for sorted[60] (4th largest)

// Midpoints between adjacent FP4 magnitude levels, +/- the f32 half-ulp at the
// midpoint: fl(q)>m <=> q>m+d (pos tie-break), fl(q)>=m <=> q>=m-d (neg).
constexpr double MP0 = 0.375 + 0x1p-26, MN0 = 0.375 - 0x1p-26;
constexpr double MP1 = 0.875 + 0x1p-25, MN1 = 0.875 - 0x1p-25;
constexpr double MP2 = 1.25 + 0x1p-24, MN2 = 1.25 - 0x1p-24;
constexpr double MP3 = 1.75 + 0x1p-24, MN3 = 1.75 - 0x1p-24;
constexpr double MP4 = 2.5 + 0x1p-23, MN4 = 2.5 - 0x1p-23;

// Smallest f32 >= sd*md (exact f64 product; never exactly an f32), making
// |x| >= thr() bit-equivalent to the reference's fl(|x|/s) vs midpoint
// compare with the tie direction baked into md.
__device__ inline float thr(double sd, double md) {
  double t = sd * md;  // exact
  float t32 = (float)t;
  return ((double)t32 < t) ? __uint_as_float(__float_as_uint(t32) + 1u) : t32;
}

// Branchless insert of v into descending top-5 list t[0]>=...>=t[4].
__device__ inline void ins5(float (&t)[5], float v) {
#pragma unroll
  for (int k = 0; k < 4; ++k) {
    float m = fmaxf(t[k], v);
    v = fminf(t[k], v);
    t[k] = m;
  }
  t[4] = fmaxf(t[4], v);
}

// 4-bit code via threshold compares: c in 0..5 (magnitude rank), +6 if neg.
__device__ inline unsigned code1t(float xv, const float (&tp)[5],
                                  const float (&tn)[5]) {
  const bool neg = xv < 0.0f;
  const float ax = fabsf(xv);
  unsigned c = neg ? 6u : 0u;
#pragma unroll
  for (int k = 0; k < 5; ++k) {
    float t = neg ? tn[k] : tp[k];
    c += (unsigned)(ax >= t);
  }
  return c;
}

// Pass 1: wave-cooperative LDS staging kills per-thread serial load chains
// (rounds 2-13: compiler keeps ~2-3 of a 16-deep per-thread load chain in
// flight -> ~60% stall). Each WG stages 64 quant blocks with 4 independent
// fully-coalesced float4 loads per thread (one vmcnt drain), then thread
// (t>>2, t&3) computes a 16-elem quarter-block from LDS (stride-65 rows,
// <=2-way bank aliasing = free), merges top-5 across 4 lanes via shfl_xor,
// and emits divide-free threshold codes as one dense uint2 per thread.
__global__ __launch_bounds__(256) void scales_k(const float4* __restrict__ x4,
                                                float* __restrict__ scales,
                                                float2* __restrict__ part,
                                                uint2* __restrict__ codes2,
                                                int nblocks, int n4) {
  __shared__ float xs[64 * 65];  // 64 blocks x 64 elems, +1 dword row pad
  __shared__ float smn[256];
  __shared__ float smx[256];
  const int t = threadIdx.x;
  const int wg = blockIdx.x;

  // Phase L: global -> LDS. 4 independent wave-linear loads (1 KB/instr).
#pragma unroll
  for (int k = 0; k < 4; ++k) {
    const int fi = wg * 1024 + k * 256 + t;  // global float4 index
    float4 v = (fi < n4) ? x4[fi] : make_float4(0.f, 0.f, 0.f, 0.f);
    const int lf = (k * 256 + t) << 2;  // local float index 0..4095
    float* dst = &xs[(lf >> 6) * 65 + (lf & 63)];
    dst[0] = v.x;
    dst[1] = v.y;
    dst[2] = v.z;
    dst[3] = v.w;
  }
  __syncthreads();

  // Phase C: quarter-block per thread.
  const int lb = t >> 2;   // local block 0..63
  const int q = t & 3;     // quarter 0..3
  const int gb = wg * 64 + lb;
  const float* row = &xs[lb * 65 + q * 16];
  float v[16];
#pragma unroll
  for (int j = 0; j < 16; ++j) v[j] = row[j];
  // Two interleaved top-5 lists; |x| >= 0 > -1 sentinel.
  float ta[5] = {-1.f, -1.f, -1.f, -1.f, -1.f};
  float tb[5] = {-1.f, -1.f, -1.f, -1.f, -1.f};
#pragma unroll
  for (int j = 0; j < 16; j += 2) {
    ins5(ta, fabsf(v[j]));
    ins5(tb, fabsf(v[j + 1]));
  }
#pragma unroll
  for (int k = 0; k < 5; ++k) ins5(ta, tb[k]);  // top-5 of my 16
  // Exact multiset merge across the block's 4 lanes (same wave).
  float pb[5];
#pragma unroll
  for (int k = 0; k < 5; ++k) pb[k] = __shfl_xor(ta[k], 1);
#pragma unroll
  for (int k = 0; k < 5; ++k) ins5(ta, pb[k]);
#pragma unroll
  for (int k = 0; k < 5; ++k) pb[k] = __shfl_xor(ta[k], 2);
#pragma unroll
  for (int k = 0; k < 5; ++k) ins5(ta, pb[k]);
  // sorted[60] = 4th largest = ta[3]; sorted[59] = 5th largest = ta[4]
  // bit-exact jax quantile: add(mul(lo,w_lo), mul(hi,w_hi)) in f32, no FMA
  float sc = __fadd_rn(__fmul_rn(ta[4], W59), __fmul_rn(ta[3], W60));
  sc = fmaxf(sc, 1e-8f);  // jnp.clip(scales, 1e-8)
  const bool valid = gb < nblocks;
  if (valid && q == 0) scales[gb] = sc;
  // Per-block divide-free thresholds (exact; see thr()).
  const double sd = (double)sc;
  float tp[5], tn[5];
  tp[0] = thr(sd, MP0);
  tn[0] = thr(sd, MN0);
  tp[1] = thr(sd, MP1);
  tn[1] = thr(sd, MN1);
  tp[2] = thr(sd, MP2);
  tn[2] = thr(sd, MN2);
  tp[3] = thr(sd, MP3);
  tn[3] = thr(sd, MN3);
  tp[4] = thr(sd, MP4);
  tn[4] = thr(sd, MN4);
  // Code my 16 elements -> 4 ushorts -> one dense uint2 (index wg*256+t).
  unsigned u0, u1, u2, u3;
  u0 = code1t(v[0], tp, tn) | (code1t(v[1], tp, tn) << 4) |
       (code1t(v[2], tp, tn) << 8) | (code1t(v[3], tp, tn) << 12);
  u1 = code1t(v[4], tp, tn) | (code1t(v[5], tp, tn) << 4) |
       (code1t(v[6], tp, tn) << 8) | (code1t(v[7], tp, tn) << 12);
  u2 = code1t(v[8], tp, tn) | (code1t(v[9], tp, tn) << 4) |
       (code1t(v[10], tp, tn) << 8) | (code1t(v[11], tp, tn) << 12);
  u3 = code1t(v[12], tp, tn) | (code1t(v[13], tp, tn) << 4) |
       (code1t(v[14], tp, tn) << 8) | (code1t(v[15], tp, tn) << 12);
  if (valid) {
    uint2 w;
    w.x = u0 | (u1 << 16);
    w.y = u2 | (u3 << 16);
    codes2[(size_t)wg * 256 + t] = w;  // ushort idx = float4 idx, dense
  }
  // Per-WG min/max of scales (dup x4 per block is harmless), one plain store.
  smn[t] = valid ? sc : __uint_as_float(0x7F800000u);
  smx[t] = valid ? sc : 0.0f;
  __syncthreads();
  if (t < 64) {
    float mn = fminf(fminf(smn[t], smn[t + 64]), fminf(smn[t + 128], smn[t + 192]));
    float mx = fmaxf(fmaxf(smx[t], smx[t + 64]), fmaxf(smx[t + 128], smx[t + 192]));
#pragma unroll
    for (int off = 32; off; off >>= 1) {
      mn = fminf(mn, __shfl_xor(mn, off));
      mx = fmaxf(mx, __shfl_xor(mx, off));
    }
    if (t == 0) part[wg] = make_float2(mn, mx);
  }
}

// Decode one 4-bit code -> level * dq (bit-exact final multiply).
__device__ inline float dec1(unsigned code, float dq) {
  unsigned m = (code >= 6u) ? code - 6u : code;
  float mag = (m == 0u) ? 0.0f
            : (m == 1u) ? 0.75f
            : (m == 2u) ? 1.0f
            : (m == 3u) ? 1.5f
            : (m == 4u) ? 2.0f
                        : 3.0f;
  float lvl = (code >= 6u) ? -mag : mag;
  return __fmul_rn(lvl, dq);
}

// Pass 2: thread <-> output float4 index (grid-stride) => coalesced 2-B code
// loads and 16-B stores (proven ~13 us in r10).
__global__ __launch_bounds__(256) void deq_k(const ushort* __restrict__ codes,
                                             const float* __restrict__ scales,
                                             const float2* __restrict__ part,
                                             float4* __restrict__ o4, int n4,
                                             int nwg) {
  __shared__ float smn[256];
  __shared__ float smx[256];
  __shared__ float bc[2];
  const int t = threadIdx.x;
  float mn = __uint_as_float(0x7F800000u);
  float mx = 0.0f;
  for (int i = t; i < nwg; i += 256) {
    float2 pr = part[i];
    mn = fminf(mn, pr.x);
    mx = fmaxf(mx, pr.y);
  }
  smn[t] = mn;
  smx[t] = mx;
  __syncthreads();
  if (t < 64) {
    float mn2 = fminf(fminf(smn[t], smn[t + 64]), fminf(smn[t + 128], smn[t + 192]));
    float mx2 = fmaxf(fmaxf(smx[t], smx[t + 64]), fmaxf(smx[t + 128], smx[t + 192]));
#pragma unroll
    for (int off = 32; off; off >>= 1) {
      mn2 = fminf(mn2, __shfl_xor(mn2, off));
      mx2 = fmaxf(mx2, __shfl_xor(mx2, off));
    }
    if (t == 0) {
      bc[0] = mn2;
      bc[1] = mx2;
    }
  }
  __syncthreads();
  const float smin = bc[0];
  const float smax = bc[1];
  const bool nd = smax > smin;
  const float ss = nd ? __fdiv_rn(__fsub_rn(smax, smin), 255.0f) : 1.0f;

  int i = blockIdx.x * 256 + t;
  const int stride = gridDim.x * 256;
  for (; i < n4; i += stride) {
    unsigned w = codes[i];
    float s = scales[i >> 4];
    float dq = 0.0f;
    if (nd) {
      float q = rintf(__fdiv_rn(__fsub_rn(s, smin), ss));  // jnp.round = RNE
      q = fminf(fmaxf(q, 0.0f), 255.0f);
      dq = __fmul_rn(q, ss);  // q_scales * scale_scale (no s_min added back)
    }
    float4 o;
    o.x = dec1(w & 15u, dq);
    o.y = dec1((w >> 4) & 15u, dq);
    o.z = dec1((w >> 8) & 15u, dq);
    o.w = dec1((w >> 12) & 15u, dq);
    o4[i] = o;
  }
}

}  // namespace

extern "C" void kernel_launch(void* const* d_in, const int* in_sizes, int n_in,
                              void* d_out, int out_size, void* d_ws, size_t ws_size,
                              hipStream_t stream) {
  const float* x = (const float*)d_in[0];
  float* out = (float*)d_out;
  const int n = in_sizes[0];
  const int nblocks = n / QBLOCK;
  const int n4 = n / 4;
  const int nwg1 = (nblocks + 63) / 64;  // 4096 for 2048x8192

  // ws layout (16-B aligned): codes | scales | partials
  uint2* codes2 = (uint2*)d_ws;                                  // 32 B/block
  float* scales = (float*)((char*)d_ws + (size_t)nblocks * 32);  // 4 B/block
  float2* part = (float2*)((char*)scales + (size_t)nblocks * 4);

  hipLaunchKernelGGL(scales_k, dim3(nwg1), dim3(256), 0, stream,
                     (const float4*)x, scales, part, codes2, nblocks, n4);
  hipLaunchKernelGGL(deq_k, dim3(2048), dim3(256), 0, stream,
                     (const ushort*)d_ws, scales, part, (float4*)out, n4, nwg1);
}

// Round 15
// 48.386 us; speedup vs baseline: 1.2106x; 1.2106x over previous
//
#include <hip/hip_runtime.h>
#include <cstdint>
#include <math.h>

namespace {

constexpr int QBLOCK = 64;
// jax: q = 0.95f * 63.0f -> f32 59.849998474121094
// high_weight = q - 59 = 0.84999847412109375 (exact), low_weight = 60 - q (exact)
constexpr float W59 = 0.15000152587890625f;  // weight for sorted[59] (5th largest)
constexpr float W60 = 0.84999847412109375f;  // weight for sorted[60] (4th largest)

// Midpoints between adjacent FP4 magnitude levels, +/- the f32 half-ulp at the
// midpoint: fl(q)>m <=> q>m+d (pos tie-break), fl(q)>=m <=> q>=m-d (neg).
constexpr double MP0 = 0.375 + 0x1p-26, MN0 = 0.375 - 0x1p-26;
constexpr double MP1 = 0.875 + 0x1p-25, MN1 = 0.875 - 0x1p-25;
constexpr double MP2 = 1.25 + 0x1p-24, MN2 = 1.25 - 0x1p-24;
constexpr double MP3 = 1.75 + 0x1p-24, MN3 = 1.75 - 0x1p-24;
constexpr double MP4 = 2.5 + 0x1p-23, MN4 = 2.5 - 0x1p-23;

// Smallest f32 >= sd*md (exact f64 product; never exactly an f32), making
// |x| >= thr() bit-equivalent to the reference's fl(|x|/s)-vs-midpoint
// compare with the tie direction baked into md.
__device__ inline float thr(double sd, double md) {
  double t = sd * md;  // exact
  float t32 = (float)t;
  return ((double)t32 < t) ? __uint_as_float(__float_as_uint(t32) + 1u) : t32;
}

// Branchless insert of v into descending top-5 list t[0]>=...>=t[4].
__device__ inline void ins5(float (&t)[5], float v) {
#pragma unroll
  for (int k = 0; k < 4; ++k) {
    float m = fmaxf(t[k], v);
    v = fminf(t[k], v);
    t[k] = m;
  }
  t[4] = fmaxf(t[4], v);
}

__device__ inline void ins4x(float (&ta)[5], float (&tb)[5], float4 u, float4 w) {
  ins5(ta, fabsf(u.x));
  ins5(tb, fabsf(w.x));
  ins5(ta, fabsf(u.y));
  ins5(tb, fabsf(w.y));
  ins5(ta, fabsf(u.z));
  ins5(tb, fabsf(w.z));
  ins5(ta, fabsf(u.w));
  ins5(tb, fabsf(w.w));
}

// 4-bit code via threshold compares: c in 0..5 (magnitude rank), +6 if neg.
__device__ inline unsigned code1t(float xv, const float (&tp)[5],
                                  const float (&tn)[5]) {
  const bool neg = xv < 0.0f;
  const float ax = fabsf(xv);
  unsigned c = neg ? 6u : 0u;
#pragma unroll
  for (int k = 0; k < 5; ++k) {
    float t = neg ? tn[k] : tp[k];
    c += (unsigned)(ax >= t);
  }
  return c;
}

__device__ inline unsigned code4t(float4 v, const float (&tp)[5],
                                  const float (&tn)[5]) {
  return code1t(v.x, tp, tn) | (code1t(v.y, tp, tn) << 4) |
         (code1t(v.z, tp, tn) << 8) | (code1t(v.w, tp, tn) << 12);
}

// Pass 1: TWO threads per 64-element quant block (32 contiguous floats each).
// Rationale (ledger r2-r14): coding ~triples VALU work, and 1-thread/block
// caps the machine at 4096 waves = 50% of wave slots -> VALU+latency can't be
// hidden (VALUBusy 41%, occ 31%, r10). 2 threads/block = 8192 waves = 100%
// slot occupancy, per-thread VALU halved; exact top-5 via one shfl_xor merge.
// NO atomics; divide-free coding; dense uint4 code store per thread.
__global__ __launch_bounds__(256) void scales_k(const float4* __restrict__ x4,
                                                float* __restrict__ scales,
                                                float2* __restrict__ part,
                                                uint4* __restrict__ codes4,
                                                int nblocks) {
  __shared__ float smn[256];
  __shared__ float smx[256];
  const int t = threadIdx.x;
  const int tid = blockIdx.x * 256 + t;
  const int b = tid >> 1;  // quant block; (tid&1) = half
  float sc_min = __uint_as_float(0x7F800000u);  // +inf
  float sc_max = 0.0f;
  if (b < nblocks) {
    const float4* p = x4 + (size_t)tid * 8;  // my 32 contiguous floats
    float4 a0 = p[0], a1 = p[1], a2 = p[2], a3 = p[3];
    float4 a4 = p[4], a5 = p[5], a6 = p[6], a7 = p[7];
    // Two interleaved top-5 lists for ILP; |x| >= 0 > -1 sentinel.
    float ta[5] = {-1.f, -1.f, -1.f, -1.f, -1.f};
    float tb[5] = {-1.f, -1.f, -1.f, -1.f, -1.f};
    ins4x(ta, tb, a0, a1);
    ins4x(ta, tb, a2, a3);
    ins4x(ta, tb, a4, a5);
    ins4x(ta, tb, a6, a7);
#pragma unroll
    for (int k = 0; k < 5; ++k) ins5(ta, tb[k]);  // top-5 of my 32
    // Exact multiset merge with the partner lane (other half of the block).
    float pb[5];
#pragma unroll
    for (int k = 0; k < 5; ++k) pb[k] = __shfl_xor(ta[k], 1);
#pragma unroll
    for (int k = 0; k < 5; ++k) ins5(ta, pb[k]);
    // sorted[60] = 4th largest = ta[3]; sorted[59] = 5th largest = ta[4]
    // bit-exact jax quantile: add(mul(lo,w_lo), mul(hi,w_hi)) in f32, no FMA
    float sc = __fadd_rn(__fmul_rn(ta[4], W59), __fmul_rn(ta[3], W60));
    sc = fmaxf(sc, 1e-8f);  // jnp.clip(scales, 1e-8)
    if ((tid & 1) == 0) scales[b] = sc;
    sc_min = sc;
    sc_max = sc;
    // Per-block divide-free thresholds (exact; see thr()).
    const double sd = (double)sc;
    float tp[5], tn[5];
    tp[0] = thr(sd, MP0);
    tn[0] = thr(sd, MN0);
    tp[1] = thr(sd, MP1);
    tn[1] = thr(sd, MN1);
    tp[2] = thr(sd, MP2);
    tn[2] = thr(sd, MN2);
    tp[3] = thr(sd, MP3);
    tn[3] = thr(sd, MN3);
    tp[4] = thr(sd, MP4);
    tn[4] = thr(sd, MN4);
    // Code my 32 elements -> 8 ushorts -> one dense uint4 at codes4[tid]
    // (ushort index == output float4 index: identity mapping for deq_k).
    uint4 w;
    w.x = code4t(a0, tp, tn) | (code4t(a1, tp, tn) << 16);
    w.y = code4t(a2, tp, tn) | (code4t(a3, tp, tn) << 16);
    w.z = code4t(a4, tp, tn) | (code4t(a5, tp, tn) << 16);
    w.w = code4t(a6, tp, tn) | (code4t(a7, tp, tn) << 16);
    codes4[tid] = w;
  }
  // Per-WG min/max (x2 duplication per block is harmless), one plain store.
  smn[t] = sc_min;
  smx[t] = sc_max;
  __syncthreads();
  if (t < 64) {
    float mn = fminf(fminf(smn[t], smn[t + 64]), fminf(smn[t + 128], smn[t + 192]));
    float mx = fmaxf(fmaxf(smx[t], smx[t + 64]), fmaxf(smx[t + 128], smx[t + 192]));
#pragma unroll
    for (int off = 32; off; off >>= 1) {
      mn = fminf(mn, __shfl_xor(mn, off));
      mx = fmaxf(mx, __shfl_xor(mx, off));
    }
    if (t == 0) part[blockIdx.x] = make_float2(mn, mx);
  }
}

// Decode one 4-bit code -> level * dq (bit-exact final multiply).
__device__ inline float dec1(unsigned code, float dq) {
  unsigned m = (code >= 6u) ? code - 6u : code;
  float mag = (m == 0u) ? 0.0f
            : (m == 1u) ? 0.75f
            : (m == 2u) ? 1.0f
            : (m == 3u) ? 1.5f
            : (m == 4u) ? 2.0f
                        : 3.0f;
  float lvl = (code >= 6u) ? -mag : mag;
  return __fmul_rn(lvl, dq);
}

// Pass 2: thread <-> output float4 index (grid-stride) => coalesced 2-B code
// loads and 16-B stores (proven ~13-14 us, r10/r13).
__global__ __launch_bounds__(256) void deq_k(const ushort* __restrict__ codes,
                                             const float* __restrict__ scales,
                                             const float2* __restrict__ part,
                                             float4* __restrict__ o4, int n4,
                                             int nwg) {
  __shared__ float smn[256];
  __shared__ float smx[256];
  __shared__ float bc[2];
  const int t = threadIdx.x;
  float mn = __uint_as_float(0x7F800000u);
  float mx = 0.0f;
  for (int i = t; i < nwg; i += 256) {
    float2 pr = part[i];
    mn = fminf(mn, pr.x);
    mx = fmaxf(mx, pr.y);
  }
  smn[t] = mn;
  smx[t] = mx;
  __syncthreads();
  if (t < 64) {
    float mn2 = fminf(fminf(smn[t], smn[t + 64]), fminf(smn[t + 128], smn[t + 192]));
    float mx2 = fmaxf(fmaxf(smx[t], smx[t + 64]), fmaxf(smx[t + 128], smx[t + 192]));
#pragma unroll
    for (int off = 32; off; off >>= 1) {
      mn2 = fminf(mn2, __shfl_xor(mn2, off));
      mx2 = fmaxf(mx2, __shfl_xor(mx2, off));
    }
    if (t == 0) {
      bc[0] = mn2;
      bc[1] = mx2;
    }
  }
  __syncthreads();
  const float smin = bc[0];
  const float smax = bc[1];
  const bool nd = smax > smin;
  const float ss = nd ? __fdiv_rn(__fsub_rn(smax, smin), 255.0f) : 1.0f;

  int i = blockIdx.x * 256 + t;
  const int stride = gridDim.x * 256;
  for (; i < n4; i += stride) {
    unsigned w = codes[i];
    float s = scales[i >> 4];
    float dq = 0.0f;
    if (nd) {
      float q = rintf(__fdiv_rn(__fsub_rn(s, smin), ss));  // jnp.round = RNE
      q = fminf(fmaxf(q, 0.0f), 255.0f);
      dq = __fmul_rn(q, ss);  // q_scales * scale_scale (no s_min added back)
    }
    float4 o;
    o.x = dec1(w & 15u, dq);
    o.y = dec1((w >> 4) & 15u, dq);
    o.z = dec1((w >> 8) & 15u, dq);
    o.w = dec1((w >> 12) & 15u, dq);
    o4[i] = o;
  }
}

}  // namespace

extern "C" void kernel_launch(void* const* d_in, const int* in_sizes, int n_in,
                              void* d_out, int out_size, void* d_ws, size_t ws_size,
                              hipStream_t stream) {
  const float* x = (const float*)d_in[0];
  float* out = (float*)d_out;
  const int n = in_sizes[0];
  const int nblocks = n / QBLOCK;
  const int n4 = n / 4;

  // ws layout (16-B aligned): codes | scales | partials
  uint4* codes4 = (uint4*)d_ws;                                  // 32 B/block
  float* scales = (float*)((char*)d_ws + (size_t)nblocks * 32);  // 4 B/block
  float2* part = (float2*)((char*)scales + (size_t)nblocks * 4);

  const long long nthreads = (long long)nblocks * 2;  // 2 threads per block
  const int nwg1 = (int)((nthreads + 255) / 256);     // 2048 for 2048x8192
  hipLaunchKernelGGL(scales_k, dim3(nwg1), dim3(256), 0, stream,
                     (const float4*)x, scales, part, codes4, nblocks);
  hipLaunchKernelGGL(deq_k, dim3(2048), dim3(256), 0, stream,
                     (const ushort*)d_ws, scales, part, (float4*)out, n4, nwg1);
}